// Round 9
// baseline (110.686 us; speedup 1.0000x reference)
//
#include <hip/hip_runtime.h>
#include <hip/hip_bf16.h>
#include <cstdint>

#define B_SZ 2048
#define T_SZ 512
#define F_SZ 64
#define BPB  2               // batch rows per block
#define TCH  16              // timesteps per chunk
#define NCHK (T_SZ / TCH)    // 32
#define NBLK (B_SZ / BPB)    // 1024 -> 4 blocks/CU
#define NTHR 128             // wave0 = scan, wave1 = MFMA; both issue stages
#define ROWS (BPB * TCH)     // 32 (b,t) rows per chunk
#define MT   (ROWS / 16)     // 2 M-tiles
#define SLOTS (ROWS * 16)    // 512 16B-slots per chunk buffer
#define GPW  4               // gload16 wave-instructions per wave per chunk
#define TSTR 44              // zbuf t-stride (floats)
#define ESTR 20              // zbuf elem-stride (floats)

#define L2E 1.4426950408889634f

typedef __attribute__((ext_vector_type(8))) short short8;
typedef __attribute__((ext_vector_type(4))) float f32x4;

__device__ __forceinline__ float fast_rcp(float x) { return __builtin_amdgcn_rcpf(x); }
__device__ __forceinline__ float exp2h(float x)    { return __builtin_amdgcn_exp2f(x); }
__device__ __forceinline__ float sigm_s(float zs)  { return fast_rcp(1.0f + exp2h(zs)); }
__device__ __forceinline__ float tanh_s(float zs)  { return fmaf(2.0f, fast_rcp(1.0f + exp2h(zs)), -1.0f); }
__device__ __forceinline__ float sigm_n(float x)   { return sigm_s(x * (-L2E)); }
__device__ __forceinline__ float tanh_n(float x)   { return tanh_s(x * (-2.0f * L2E)); }

__device__ __forceinline__ unsigned short f2bf(float f) {
    __hip_bfloat16 h = (__hip_bfloat16)f;   // RNE
    return *reinterpret_cast<unsigned short*>(&h);
}

template<int CTRL>
__device__ __forceinline__ float qperm(float v) {
    return __int_as_float(__builtin_amdgcn_mov_dpp(__float_as_int(v), CTRL, 0xF, 0xF, false));
}
#define QPA 9    // lane k <- src[{1,2,0,0}[k]]  -> h_{(m+1)%3}
#define QPB 82   // lane k <- src[{2,0,1,1}[k]]  -> h_{(m+2)%3}

// direct HBM -> LDS, 16B/lane; LDS dest = wave-uniform base + lane*16
__device__ __forceinline__ void gload16(const float* g, void* l) {
    __builtin_amdgcn_global_load_lds(
        (const __attribute__((address_space(1))) void*)g,
        (__attribute__((address_space(3))) void*)l, 16, 0, 0);
}

__global__ __launch_bounds__(NTHR) void lstm_mfma(const float* __restrict__ x,
                                                  const float* __restrict__ W,
                                                  const float* __restrict__ U,
                                                  const float* __restrict__ bias,
                                                  const float* __restrict__ Wd,
                                                  const float* __restrict__ bdp,
                                                  float* __restrict__ out) {
    // x chunk buffers (fp32, source-swizzled): slot s holds logical 16B-block
    // (s&15)^(row&15) of row s>>4.  3 x 8 KB triple buffer.
    __shared__ float xls[3][SLOTS * 4];
    __shared__ float zbuf[2][TCH * TSTR];    // 2 x 2.75 KB

    const int tid = threadIdx.x;
    const int wv  = tid >> 6;
    const int ln  = tid & 63;
    const int b0  = blockIdx.x * BPB;

    // ---- gate mapping: MFMA col n = gate p = mm*4+q  <-  W col q*3+mm ----
    const int n  = ln & 15;
    const int q  = n & 3, mm = n >> 2;
    const float sc = (q == 2) ? (-2.0f * L2E) : (-L2E);

    // ---- B-fragments: W stationary in VGPRs ----
    short8 bfrag[2];
    #pragma unroll
    for (int kt = 0; kt < 2; ++kt) {
        short8 s;
        #pragma unroll
        for (int e = 0; e < 8; ++e) {
            const int hh = e >> 2, j = e & 3;
            const int kk = kt * 32 + hh * 16 + 4 * (ln >> 4) + j;
            const float w = (n < 12) ? W[kk * 12 + q * 3 + mm] * sc : 0.0f;
            s[e] = (short)f2bf(w);
        }
        bfrag[kt] = s;
    }
    const float bias_s = (n < 12) ? bias[q * 3 + mm] * sc : 0.0f;

    // ---- scan constants (wave 0; quad-local, dual chain A=elem0, B=elem1) ----
    const int lk = ln & 3;
    const int m  = (lk < 3) ? lk : 2;
    const int mn = (m + 1 == 3) ? 0 : m + 1;
    const int mp = (m + 2 >= 3) ? m - 1 : m + 2;
    float u_own[4], u_nxt[4], u_prv[4];
    #pragma unroll
    for (int qq = 0; qq < 4; ++qq) {
        const float scq = (qq == 2) ? (-2.0f * L2E) : (-L2E);
        const int col = qq * 3 + m;
        u_own[qq] = U[m  * 12 + col] * scq;
        u_nxt[qq] = U[mn * 12 + col] * scq;
        u_prv[qq] = U[mp * 12 + col] * scq;
    }
    float hA_ = 0.f, cA_ = 0.f, hAa = 0.f, hAb = 0.f;   // chain A state
    float hB_ = 0.f, cB_ = 0.f, hBa = 0.f, hBb = 0.f;   // chain B state

    auto comp = [&](const float4& z4, float& h, float& c, float& ha, float& hb) {
        const float z0 = fmaf(h, u_own[0], z4.x) + fmaf(ha, u_nxt[0], hb * u_prv[0]);
        const float z1 = fmaf(h, u_own[1], z4.y) + fmaf(ha, u_nxt[1], hb * u_prv[1]);
        const float z2 = fmaf(h, u_own[2], z4.z) + fmaf(ha, u_nxt[2], hb * u_prv[2]);
        const float z3 = fmaf(h, u_own[3], z4.w) + fmaf(ha, u_nxt[3], hb * u_prv[3]);
        const float ai = sigm_s(z0);
        const float af = sigm_s(z1);
        const float ag = tanh_s(z2);
        const float ao = sigm_s(z3);
        c = fmaf(af, c, ai * ag);
        h = ao * tanh_n(c);
        ha = qperm<QPA>(h);
        hb = qperm<QPB>(h);
    };
    auto scan_chunk = [&](const float* zb) {
        #pragma unroll
        for (int tt = 0; tt < TCH; ++tt) {
            const float4 zA = *reinterpret_cast<const float4*>(zb + tt * TSTR + 0 * ESTR + m * 4);
            const float4 zB = *reinterpret_cast<const float4*>(zb + tt * TSTR + 1 * ESTR + m * 4);
            comp(zA, hA_, cA_, hAa, hAb);     // two independent chains -> ILP 2
            comp(zB, hB_, cB_, hBa, hBb);
        }
    };

    // ---- stage: 8 gload16 wave-instrs per chunk (4 per wave), swizzled source ----
    auto stage = [&](int ck) {
        const int buf = ck % 3;
        const int t0  = ck * TCH;
        #pragma unroll
        for (int i = 0; i < GPW; ++i) {
            const int grp = wv * GPW + i;              // 0..7
            const int s   = grp * 64 + ln;             // slot
            const int row = s >> 4;                    // b*16 + t
            const int blk = (s & 15) ^ (row & 15);     // pre-swizzled source block
            const float* g = x + ((size_t)(b0 + (row >> 4)) * T_SZ + (t0 + (row & 15))) * F_SZ + blk * 4;
            gload16(g, &xls[buf][grp * 256]);          // 1 KB per wave-instr, linear dest
        }
    };

    auto mfma_chunk = [&](int buf, int zb) {
        #pragma unroll
        for (int mt = 0; mt < MT; ++mt) {
            f32x4 acc = { bias_s, bias_s, bias_s, bias_s };
            const int r = mt * 16 + (ln & 15);
            #pragma unroll
            for (int kt = 0; kt < 2; ++kt) {
                const int j0 = kt * 8 + (ln >> 4);
                const float4 v0 = *reinterpret_cast<const float4*>(&xls[buf][(r * 16 + ((j0    ) ^ (r & 15))) * 4]);
                const float4 v1 = *reinterpret_cast<const float4*>(&xls[buf][(r * 16 + ((j0 + 4) ^ (r & 15))) * 4]);
                short8 a;
                a[0] = (short)f2bf(v0.x); a[1] = (short)f2bf(v0.y);
                a[2] = (short)f2bf(v0.z); a[3] = (short)f2bf(v0.w);
                a[4] = (short)f2bf(v1.x); a[5] = (short)f2bf(v1.y);
                a[6] = (short)f2bf(v1.z); a[7] = (short)f2bf(v1.w);
                acc = __builtin_amdgcn_mfma_f32_16x16x32_bf16(a, bfrag[kt], acc, 0, 0, 0);
            }
            #pragma unroll
            for (int ri = 0; ri < 4; ++ri) {
                const int tt = 4 * (ln >> 4) + ri;     // timestep within chunk
                zbuf[zb][tt * TSTR + mt * ESTR + n] = acc[ri];
            }
        }
    };

    // ---- prologue: two chunks in flight before first barrier ----
    stage(0);
    stage(1);
    asm volatile("s_waitcnt vmcnt(4)" ::: "memory");    // chunk 0 landed; chunk 1 in flight
    __builtin_amdgcn_sched_barrier(0);
    __builtin_amdgcn_s_barrier();
    __builtin_amdgcn_sched_barrier(0);

    // ---- pipeline: issue(k+2) | mfma z(k) / scan(k-1) | counted-vmcnt barrier ----
    for (int k = 0; k < NCHK; ++k) {
        if (k + 2 < NCHK) stage(k + 2);
        const int cur = k % 3, zb = k & 1;

        if (wv == 1) mfma_chunk(cur, zb);
        else if (k > 0) scan_chunk(zbuf[zb ^ 1]);

        if (k + 2 < NCHK) asm volatile("s_waitcnt vmcnt(4) lgkmcnt(0)" ::: "memory");
        else              asm volatile("s_waitcnt vmcnt(0) lgkmcnt(0)" ::: "memory");
        __builtin_amdgcn_sched_barrier(0);
        __builtin_amdgcn_s_barrier();
        __builtin_amdgcn_sched_barrier(0);
    }

    // ---- epilogue: scan last chunk + dense head ----
    if (wv == 0) {
        scan_chunk(zbuf[(NCHK - 1) & 1]);
        if (ln == 0) {
            const float lA = bdp[0] + hA_ * Wd[m] + hAa * Wd[mn] + hAb * Wd[mp];
            const float lB = bdp[0] + hB_ * Wd[m] + hBa * Wd[mn] + hBb * Wd[mp];
            out[b0 + 0] = sigm_n(lA);
            out[b0 + 1] = sigm_n(lB);
        }
    }
}

extern "C" void kernel_launch(void* const* d_in, const int* in_sizes, int n_in,
                              void* d_out, int out_size, void* d_ws, size_t ws_size,
                              hipStream_t stream) {
    (void)in_sizes; (void)n_in; (void)out_size; (void)d_ws; (void)ws_size;
    const float* x  = (const float*)d_in[0];
    const float* W  = (const float*)d_in[1];
    const float* U  = (const float*)d_in[2];
    const float* b  = (const float*)d_in[3];
    const float* Wd = (const float*)d_in[4];
    const float* bd = (const float*)d_in[5];
    float* out = (float*)d_out;

    lstm_mfma<<<NBLK, NTHR, 0, stream>>>(x, W, U, b, Wd, bd, out);
}

// Round 10
// 107.422 us; speedup vs baseline: 1.0304x; 1.0304x over previous
//
#include <hip/hip_runtime.h>
#include <hip/hip_bf16.h>
#include <cstdint>

#define B_SZ 2048
#define T_SZ 512
#define F_SZ 64
#define BPB  4              // batch rows per block
#define TCH  32             // timesteps per chunk
#define NCHK (T_SZ / TCH)   // 16
#define NBLK (B_SZ / BPB)   // 512 -> 2 blocks/CU
#define NTHR 256            // wv0 scan, wv1 MFMA, wv2-3 staging
#define ROWS (BPB * TCH)    // 128 rows (b,t) per chunk
#define MT   (ROWS / 16)    // 8 M-tiles
#define NPC  (ROWS * 16)    // 2048 float4 staging pieces per chunk
#define NSTG 128            // staging threads (wv2+wv3)
#define PPT  (NPC / NSTG)   // 16 pieces per staging thread
#define TSTR 84             // zbuf t-stride (floats)
#define ESTR 20             // zbuf b-elem stride (floats)

#define L2E 1.4426950408889634f

typedef __attribute__((ext_vector_type(8))) short short8;
typedef __attribute__((ext_vector_type(4))) float f32x4;

__device__ __forceinline__ float fast_rcp(float x) { return __builtin_amdgcn_rcpf(x); }
__device__ __forceinline__ float exp2h(float x)    { return __builtin_amdgcn_exp2f(x); }
__device__ __forceinline__ float sigm_s(float zs)  { return fast_rcp(1.0f + exp2h(zs)); }
__device__ __forceinline__ float tanh_s(float zs)  { return fmaf(2.0f, fast_rcp(1.0f + exp2h(zs)), -1.0f); }
__device__ __forceinline__ float sigm_n(float x)   { return sigm_s(x * (-L2E)); }
__device__ __forceinline__ float tanh_n(float x)   { return tanh_s(x * (-2.0f * L2E)); }

__device__ __forceinline__ unsigned short f2bf(float f) {
    __hip_bfloat16 h = (__hip_bfloat16)f;   // RNE
    return *reinterpret_cast<unsigned short*>(&h);
}

template<int CTRL>
__device__ __forceinline__ float qperm(float v) {
    return __int_as_float(__builtin_amdgcn_mov_dpp(__float_as_int(v), CTRL, 0xF, 0xF, false));
}
#define QPA 9    // lane k <- src[{1,2,0,0}[k]]  -> h_{(m+1)%3}
#define QPB 82   // lane k <- src[{2,0,1,1}[k]]  -> h_{(m+2)%3}

__global__ __launch_bounds__(NTHR) void lstm_mfma(const float* __restrict__ x,
                                                  const float* __restrict__ W,
                                                  const float* __restrict__ U,
                                                  const float* __restrict__ bias,
                                                  const float* __restrict__ Wd,
                                                  const float* __restrict__ bdp,
                                                  float* __restrict__ out) {
    // A-fragment-ordered x (bf16): per (Mtile,Ktile): 64 lanes x 16B
    __shared__ unsigned int xfrag[2][MT * 2 * 256];   // 2 x 16 KB
    __shared__ float zbuf[2][TCH * TSTR];             // 2 x 10.75 KB

    const int tid = threadIdx.x;
    const int wv  = tid >> 6;
    const int ln  = tid & 63;
    const int b0  = blockIdx.x * BPB;

    // ---- per-lane gate mapping (gate p = mm*4+q <- W col q*3+mm), scaled ----
    const int n  = ln & 15;                 // MFMA col = gate index (12 real + 4 pad)
    const int q  = n & 3, mm = n >> 2;
    const float sc = (q == 2) ? (-2.0f * L2E) : (-L2E);

    // ---- B-fragments: W stationary in VGPRs (wv1 only uses them) ----
    short8 bfrag[2];
    #pragma unroll
    for (int kt = 0; kt < 2; ++kt) {
        short8 s;
        #pragma unroll
        for (int e = 0; e < 8; ++e) {
            const int hh = e >> 2, j = e & 3;
            const int kk = kt * 32 + hh * 16 + 4 * (ln >> 4) + j;   // f index
            const float w = (n < 12 && wv == 1) ? W[kk * 12 + q * 3 + mm] * sc : 0.0f;
            s[e] = (short)f2bf(w);
        }
        bfrag[kt] = s;
    }
    const float bias_s = (n < 12) ? bias[q * 3 + mm] * sc : 0.0f;

    // ---- scan constants (wv0; lanes 0..7: dual chain, elems 2*e2 and 2*e2+1) ----
    const int lk = ln & 3;
    const int m  = (lk < 3) ? lk : 2;
    const int mn = (m + 1 == 3) ? 0 : m + 1;
    const int mp = (m + 2 >= 3) ? m - 1 : m + 2;
    const int e2 = (ln >> 2) & 1;           // chain pair selector
    float u_own[4], u_nxt[4], u_prv[4];
    #pragma unroll
    for (int qq = 0; qq < 4; ++qq) {
        const float scq = (qq == 2) ? (-2.0f * L2E) : (-L2E);
        const int col = qq * 3 + m;
        u_own[qq] = U[m  * 12 + col] * scq;
        u_nxt[qq] = U[mn * 12 + col] * scq;
        u_prv[qq] = U[mp * 12 + col] * scq;
    }
    float hA_ = 0.f, cA_ = 0.f, hAa = 0.f, hAb = 0.f;   // chain A (elem 2*e2)
    float hB_ = 0.f, cB_ = 0.f, hBa = 0.f, hBb = 0.f;   // chain B (elem 2*e2+1)

    auto comp = [&](const float4& z4, float& h, float& c, float& ha, float& hb) {
        const float z0 = fmaf(h, u_own[0], z4.x) + fmaf(ha, u_nxt[0], hb * u_prv[0]);
        const float z1 = fmaf(h, u_own[1], z4.y) + fmaf(ha, u_nxt[1], hb * u_prv[1]);
        const float z2 = fmaf(h, u_own[2], z4.z) + fmaf(ha, u_nxt[2], hb * u_prv[2]);
        const float z3 = fmaf(h, u_own[3], z4.w) + fmaf(ha, u_nxt[3], hb * u_prv[3]);
        const float ai = sigm_s(z0);
        const float af = sigm_s(z1);
        const float ag = tanh_s(z2);
        const float ao = sigm_s(z3);
        c = fmaf(af, c, ai * ag);
        h = ao * tanh_n(c);
        ha = qperm<QPA>(h);
        hb = qperm<QPB>(h);
    };
    auto scan32 = [&](const float* zb) {
        __builtin_amdgcn_s_setprio(1);
        #pragma unroll
        for (int tt = 0; tt < TCH; ++tt) {
            const float4 zA = *reinterpret_cast<const float4*>(zb + tt * TSTR + (2 * e2 + 0) * ESTR + m * 4);
            const float4 zB = *reinterpret_cast<const float4*>(zb + tt * TSTR + (2 * e2 + 1) * ESTR + m * 4);
            comp(zA, hA_, cA_, hAa, hAb);   // two independent chains -> ILP 2
            comp(zB, hB_, cB_, hBa, hBb);
        }
        __builtin_amdgcn_s_setprio(0);
    };

    // ---- staging (wv2-3 only): issue-early global loads, convert+write bf16 A-frags ----
    float4 v[PPT];
    const int stid = tid - 128;             // 0..127 for wv2-3
    auto stage_issue = [&](int ck) {
        const int t0 = ck * TCH;
        #pragma unroll
        for (int i = 0; i < PPT; ++i) {
            const int piece = i * NSTG + stid;
            const int row = piece >> 4, g = piece & 15;
            v[i] = *reinterpret_cast<const float4*>(
                x + ((size_t)(b0 + (row >> 5)) * T_SZ + (t0 + (row & 31))) * F_SZ + (g << 2));
        }
    };
    auto stage_write = [&](int buf) {
        #pragma unroll
        for (int i = 0; i < PPT; ++i) {
            const int piece = i * NSTG + stid;
            const int row = piece >> 4, g = piece & 15;
            const int u_off = ((row >> 4) * 2 + (g >> 3)) * 256
                            + (((row & 15) | ((g & 3) << 4)) << 2) + ((g >> 2) & 1) * 2;
            uint2 pk;
            pk.x = (unsigned)f2bf(v[i].x) | ((unsigned)f2bf(v[i].y) << 16);
            pk.y = (unsigned)f2bf(v[i].z) | ((unsigned)f2bf(v[i].w) << 16);
            *reinterpret_cast<uint2*>(&xfrag[buf][u_off]) = pk;
        }
    };

    auto mfma_chunk = [&](int cur) {
        #pragma unroll
        for (int mt = 0; mt < MT; ++mt) {
            f32x4 acc = { bias_s, bias_s, bias_s, bias_s };
            const short8 a0 = *reinterpret_cast<const short8*>(&xfrag[cur][(mt * 2 + 0) * 256 + (ln << 2)]);
            const short8 a1 = *reinterpret_cast<const short8*>(&xfrag[cur][(mt * 2 + 1) * 256 + (ln << 2)]);
            acc = __builtin_amdgcn_mfma_f32_16x16x32_bf16(a0, bfrag[0], acc, 0, 0, 0);
            acc = __builtin_amdgcn_mfma_f32_16x16x32_bf16(a1, bfrag[1], acc, 0, 0, 0);
            const int rbase = mt * 16 + 4 * (ln >> 4);
            #pragma unroll
            for (int r = 0; r < 4; ++r) {
                const int rr = rbase + r;                 // row = b*32 + t
                zbuf[cur][(rr & 31) * TSTR + (rr >> 5) * ESTR + n] = acc[r];
            }
        }
    };

    // ---- prologue: staging waves fill chunk 0 ----
    if (wv >= 2) { stage_issue(0); stage_write(0); }
    __syncthreads();

    // ---- pipeline: staging(k+1) || mfma z(k) || scan(k-1), one barrier/chunk ----
    for (int k = 0; k < NCHK; ++k) {
        const int cur = k & 1;
        if (wv >= 2) {
            if (k + 1 < NCHK) { stage_issue(k + 1); stage_write(cur ^ 1); }
        } else if (wv == 1) {
            mfma_chunk(cur);
        } else if (k > 0) {
            scan32(zbuf[cur ^ 1]);
        }
        __syncthreads();
    }

    // ---- epilogue: scan last chunk + dense head ----
    if (wv == 0) {
        scan32(zbuf[(NCHK - 1) & 1]);
        if ((ln & 3) == 0 && ln < 8) {
            const float lA = bdp[0] + hA_ * Wd[m] + hAa * Wd[mn] + hAb * Wd[mp];
            const float lB = bdp[0] + hB_ * Wd[m] + hBa * Wd[mn] + hBb * Wd[mp];
            out[b0 + 2 * e2 + 0] = sigm_n(lA);
            out[b0 + 2 * e2 + 1] = sigm_n(lB);
        }
    }
}

extern "C" void kernel_launch(void* const* d_in, const int* in_sizes, int n_in,
                              void* d_out, int out_size, void* d_ws, size_t ws_size,
                              hipStream_t stream) {
    (void)in_sizes; (void)n_in; (void)out_size; (void)d_ws; (void)ws_size;
    const float* x  = (const float*)d_in[0];
    const float* W  = (const float*)d_in[1];
    const float* U  = (const float*)d_in[2];
    const float* b  = (const float*)d_in[3];
    const float* Wd = (const float*)d_in[4];
    const float* bd = (const float*)d_in[5];
    float* out = (float*)d_out;

    lstm_mfma<<<NBLK, NTHR, 0, stream>>>(x, W, U, b, Wd, bd, out);
}

// Round 11
// 68.304 us; speedup vs baseline: 1.6205x; 1.5727x over previous
//
#include <hip/hip_runtime.h>
#include <hip/hip_bf16.h>
#include <cstdint>

#define B_SZ 2048
#define T_SZ 512
#define F_SZ 64
#define BPB  4              // batch rows per block
#define TCH  32             // timesteps per chunk
#define NCHK (T_SZ / TCH)   // 16
#define NBLK (B_SZ / BPB)   // 512 -> 2 blocks/CU
#define NTHR 256            // wv0 scan, wv1 MFMA, wv2-3 staging
#define ROWS (BPB * TCH)    // 128 rows (b,t) per chunk
#define MT   (ROWS / 16)    // 8 M-tiles
#define NPC  (ROWS * 16)    // 2048 float4 staging pieces per chunk
#define NSTG 128            // staging threads (wv2+wv3)
#define PPT  (NPC / NSTG)   // 16 pieces per staging thread
#define TSTR 84             // zbuf t-stride (floats)
#define ESTR 20             // zbuf b-elem stride (floats)

#define L2E 1.4426950408889634f

typedef __attribute__((ext_vector_type(8))) short short8;
typedef __attribute__((ext_vector_type(4))) float f32x4;

__device__ __forceinline__ float fast_rcp(float x) { return __builtin_amdgcn_rcpf(x); }
__device__ __forceinline__ float exp2h(float x)    { return __builtin_amdgcn_exp2f(x); }
__device__ __forceinline__ float sigm_s(float zs)  { return fast_rcp(1.0f + exp2h(zs)); }
__device__ __forceinline__ float sigm_n(float x)   { return sigm_s(x * (-L2E)); }

__device__ __forceinline__ unsigned short f2bf(float f) {
    __hip_bfloat16 h = (__hip_bfloat16)f;   // RNE
    return *reinterpret_cast<unsigned short*>(&h);
}

template<int CTRL>
__device__ __forceinline__ float qperm(float v) {
    return __int_as_float(__builtin_amdgcn_mov_dpp(__float_as_int(v), CTRL, 0xF, 0xF, false));
}
#define QPA 9    // lane k <- src[{1,2,0,0}[k]]  -> h_{(m+1)%3}
#define QPB 82   // lane k <- src[{2,0,1,1}[k]]  -> h_{(m+2)%3}

__global__ __launch_bounds__(NTHR) void lstm_mfma(const float* __restrict__ x,
                                                  const float* __restrict__ W,
                                                  const float* __restrict__ U,
                                                  const float* __restrict__ bias,
                                                  const float* __restrict__ Wd,
                                                  const float* __restrict__ bdp,
                                                  float* __restrict__ out) {
    // A-fragment-ordered x (bf16): per (Mtile,Ktile): 64 lanes x 16B
    __shared__ unsigned int xfrag[2][MT * 2 * 256];   // 2 x 16 KB
    __shared__ float zbuf[2][TCH * TSTR];             // 2 x 10.75 KB

    const int tid = threadIdx.x;
    const int wv  = tid >> 6;
    const int ln  = tid & 63;
    const int b0  = blockIdx.x * BPB;

    // ---- per-lane gate mapping (gate p = mm*4+q <- W col q*3+mm), scaled ----
    const int n  = ln & 15;                 // MFMA col = gate index (12 real + 4 pad)
    const int q  = n & 3, mm = n >> 2;
    const float sc = (q == 2) ? (-2.0f * L2E) : (-L2E);

    // ---- B-fragments: W stationary in VGPRs (wv1 only uses them) ----
    short8 bfrag[2];
    #pragma unroll
    for (int kt = 0; kt < 2; ++kt) {
        short8 s;
        #pragma unroll
        for (int e = 0; e < 8; ++e) {
            const int hh = e >> 2, j = e & 3;
            const int kk = kt * 32 + hh * 16 + 4 * (ln >> 4) + j;   // f index
            const float w = (n < 12 && wv == 1) ? W[kk * 12 + q * 3 + mm] * sc : 0.0f;
            s[e] = (short)f2bf(w);
        }
        bfrag[kt] = s;
    }
    const float bias_s = (n < 12) ? bias[q * 3 + mm] * sc : 0.0f;

    // ---- scan constants (wv0; lanes 0..15: elems 0..3, one chain per lane) ----
    const int lk = ln & 3;
    const int m  = (lk < 3) ? lk : 2;
    const int mn = (m + 1 == 3) ? 0 : m + 1;
    const int mp = (m + 2 >= 3) ? m - 1 : m + 2;
    const int e8 = (ln >> 2) & 3;           // batch elem 0..3
    float u_own[4], u_nxt[4], u_prv[4];
    #pragma unroll
    for (int qq = 0; qq < 4; ++qq) {
        const float scq = (qq == 2) ? (-2.0f * L2E) : (-L2E);
        const int col = qq * 3 + m;
        u_own[qq] = U[m  * 12 + col] * scq;
        u_nxt[qq] = U[mn * 12 + col] * scq;
        u_prv[qq] = U[mp * 12 + col] * scq;
    }
    // state: h (natural), cs = -2*L2E*c (scaled domain), hA/hB = quad-neighbors' h
    float h = 0.f, cs = 0.f, hA = 0.f, hB = 0.f;

    // one scan step; z4 already holds pre-scaled gate pre-activations
    auto comp = [&](const float4& z4) {
        const float z0 = fmaf(h, u_own[0], z4.x) + fmaf(hA, u_nxt[0], hB * u_prv[0]);
        const float z1 = fmaf(h, u_own[1], z4.y) + fmaf(hA, u_nxt[1], hB * u_prv[1]);
        const float z2 = fmaf(h, u_own[2], z4.z) + fmaf(hA, u_nxt[2], hB * u_prv[2]);
        const float z3 = fmaf(h, u_own[3], z4.w) + fmaf(hA, u_nxt[3], hB * u_prv[3]);
        const float ai = sigm_s(z0);
        const float af = sigm_s(z1);
        // ag scaled by -2*L2E, folded into the rational form (off the cs chain):
        // tanh_s(z2)*(-2*L2E) = (2*rcp(1+e)-1)*(-2*L2E) = fma(-4*L2E, rcp(1+e), 2*L2E)
        const float agS = fmaf(-4.0f * L2E, fast_rcp(1.0f + exp2h(z2)), 2.0f * L2E);
        const float ao = sigm_s(z3);
        cs = fmaf(af, cs, ai * agS);
        // tanh(c) from scaled cs directly: 2*rcp(1+exp2(cs)) - 1
        const float th = fmaf(2.0f, fast_rcp(1.0f + exp2h(cs)), -1.0f);
        h = ao * th;
        hA = qperm<QPA>(h);
        hB = qperm<QPB>(h);
    };

    auto scan32 = [&](const float* zb) {
        const float* zp = zb + e8 * ESTR + m * 4;
        float4 pf[8];
        #pragma unroll
        for (int i = 0; i < 8; ++i)
            pf[i] = *reinterpret_cast<const float4*>(zp + i * TSTR);
        __builtin_amdgcn_s_setprio(1);
        #pragma unroll
        for (int tt = 0; tt < TCH; ++tt) {           // static unroll -> pf in regs
            const float4 z4 = pf[tt & 7];
            if (tt + 8 < TCH)
                pf[tt & 7] = *reinterpret_cast<const float4*>(zp + (tt + 8) * TSTR);
            comp(z4);
        }
        __builtin_amdgcn_s_setprio(0);
    };

    // ---- staging (wv2-3 only): issue-early global loads, convert+write bf16 A-frags ----
    float4 v[PPT];
    const int stid = tid - 128;             // 0..127 for wv2-3
    auto stage_issue = [&](int ck) {
        const int t0 = ck * TCH;
        #pragma unroll
        for (int i = 0; i < PPT; ++i) {
            const int piece = i * NSTG + stid;
            const int row = piece >> 4, g = piece & 15;
            v[i] = *reinterpret_cast<const float4*>(
                x + ((size_t)(b0 + (row >> 5)) * T_SZ + (t0 + (row & 31))) * F_SZ + (g << 2));
        }
    };
    auto stage_write = [&](int buf) {
        #pragma unroll
        for (int i = 0; i < PPT; ++i) {
            const int piece = i * NSTG + stid;
            const int row = piece >> 4, g = piece & 15;
            const int u_off = ((row >> 4) * 2 + (g >> 3)) * 256
                            + (((row & 15) | ((g & 3) << 4)) << 2) + ((g >> 2) & 1) * 2;
            uint2 pk;
            pk.x = (unsigned)f2bf(v[i].x) | ((unsigned)f2bf(v[i].y) << 16);
            pk.y = (unsigned)f2bf(v[i].z) | ((unsigned)f2bf(v[i].w) << 16);
            *reinterpret_cast<uint2*>(&xfrag[buf][u_off]) = pk;
        }
    };

    auto mfma_chunk = [&](int cur) {
        #pragma unroll
        for (int mt = 0; mt < MT; ++mt) {
            f32x4 acc = { bias_s, bias_s, bias_s, bias_s };
            const short8 a0 = *reinterpret_cast<const short8*>(&xfrag[cur][(mt * 2 + 0) * 256 + (ln << 2)]);
            const short8 a1 = *reinterpret_cast<const short8*>(&xfrag[cur][(mt * 2 + 1) * 256 + (ln << 2)]);
            acc = __builtin_amdgcn_mfma_f32_16x16x32_bf16(a0, bfrag[0], acc, 0, 0, 0);
            acc = __builtin_amdgcn_mfma_f32_16x16x32_bf16(a1, bfrag[1], acc, 0, 0, 0);
            const int rbase = mt * 16 + 4 * (ln >> 4);
            #pragma unroll
            for (int r = 0; r < 4; ++r) {
                const int rr = rbase + r;                 // row = b*32 + t
                zbuf[cur][(rr & 31) * TSTR + (rr >> 5) * ESTR + n] = acc[r];
            }
        }
    };

    // ---- prologue: staging waves fill chunk 0 ----
    if (wv >= 2) { stage_issue(0); stage_write(0); }
    __syncthreads();

    // ---- pipeline: staging(k+1) || mfma z(k) || scan(k-1), one barrier/chunk ----
    for (int k = 0; k < NCHK; ++k) {
        const int cur = k & 1;
        if (wv >= 2) {
            if (k + 1 < NCHK) { stage_issue(k + 1); stage_write(cur ^ 1); }
        } else if (wv == 1) {
            mfma_chunk(cur);
        } else if (k > 0) {
            scan32(zbuf[cur ^ 1]);
        }
        __syncthreads();
    }

    // ---- epilogue: scan last chunk + dense head ----
    if (wv == 0) {
        scan32(zbuf[(NCHK - 1) & 1]);
        if (lk == 0 && ln < 16) {
            const float logit = bdp[0] + h * Wd[m] + hA * Wd[mn] + hB * Wd[mp];
            out[b0 + e8] = sigm_n(logit);
        }
    }
}

extern "C" void kernel_launch(void* const* d_in, const int* in_sizes, int n_in,
                              void* d_out, int out_size, void* d_ws, size_t ws_size,
                              hipStream_t stream) {
    (void)in_sizes; (void)n_in; (void)out_size; (void)d_ws; (void)ws_size;
    const float* x  = (const float*)d_in[0];
    const float* W  = (const float*)d_in[1];
    const float* U  = (const float*)d_in[2];
    const float* b  = (const float*)d_in[3];
    const float* Wd = (const float*)d_in[4];
    const float* bd = (const float*)d_in[5];
    float* out = (float*)d_out;

    lstm_mfma<<<NBLK, NTHR, 0, stream>>>(x, W, U, b, Wd, bd, out);
}